// Round 1
// baseline (1323.976 us; speedup 1.0000x reference)
//
#include <hip/hip_runtime.h>

// Problem constants (fixed by setup_inputs)
#define BATCH 4
#define DDIM 256
#define LLEN 4096
#define NTOK (BATCH * LLEN)   // 16384
#define KCODE 8192
#define COMMITMENT 0.25f

// ---------------------------------------------------------------------------
// Kernel 1: per-code reciprocal L2 norm of codebook; also zero loss accum.
// One wave (64 lanes) per code; 4 codes per 256-thread block.
// ---------------------------------------------------------------------------
__global__ __launch_bounds__(256) void rnorm_kernel(
    const float* __restrict__ cb, float* __restrict__ rnorm,
    float* __restrict__ loss_accum) {
  int wave = threadIdx.x >> 6;
  int lane = threadIdx.x & 63;
  int k = blockIdx.x * 4 + wave;
  const float4 v = *(const float4*)(cb + (size_t)k * DDIM + lane * 4);
  float s = v.x * v.x + v.y * v.y + v.z * v.z + v.w * v.w;
#pragma unroll
  for (int off = 32; off > 0; off >>= 1) s += __shfl_down(s, off);
  if (lane == 0) rnorm[k] = 1.0f / sqrtf(s);
  if (blockIdx.x == 0 && threadIdx.x == 0) *loss_accum = 0.0f;
}

// ---------------------------------------------------------------------------
// Kernel 2: fused sim-GEMM + argmax.
// Tile: 64 tokens (full D resident in LDS) x 64 codes per k-tile.
// Grid: (256 token-blocks, 2 K-halves). 256 threads = 16 tx (codes) x 16 ty
// (tokens), 4x4 fp32 accumulators per thread. rnorm applied post-accum.
// ---------------------------------------------------------------------------
__global__ __launch_bounds__(256, 2) void simmax_kernel(
    const float* __restrict__ x, const float* __restrict__ cb,
    const float* __restrict__ rnorm, float* __restrict__ bestv,
    int* __restrict__ besti) {
  __shared__ float A[DDIM * 64];   // A[d][token], 64 KB
  __shared__ float Bs[32 * 68];    // Bs[dloc][code], padded stride 68 (8.7 KB)

  const int tid = threadIdx.x;
  const int blk = blockIdx.x;  // token block
  const int ks = blockIdx.y;   // K half
  const int n0 = blk * 64;
  const int b = n0 >> 12;      // /4096
  const int l0 = n0 & 4095;
  const float* xb = x + ((size_t)b << 20);  // b * D * L

  // Stage A: A[d][t] = x[b][d][l0+t] for all d. float4 loads, b128 LDS writes.
  {
    const int t4 = tid & 15;        // token quad
    const int dof = tid >> 4;       // 0..15
#pragma unroll
    for (int p = 0; p < 16; ++p) {
      int d = p * 16 + dof;
      float4 v = *(const float4*)(xb + (size_t)d * LLEN + l0 + t4 * 4);
      *(float4*)(&A[d * 64 + t4 * 4]) = v;
    }
  }
  __syncthreads();

  const int tx = tid & 15;
  const int ty = tid >> 4;

  float bv[4];
  int bi[4];
#pragma unroll
  for (int i = 0; i < 4; ++i) { bv[i] = -1e30f; bi[i] = 0; }

  const int kbase = ks * (KCODE / 2);

  for (int kt = 0; kt < (KCODE / 2) / 64; ++kt) {
    const int k0 = kbase + kt * 64;
    float acc[4][4];
#pragma unroll
    for (int i = 0; i < 4; ++i)
#pragma unroll
      for (int j = 0; j < 4; ++j) acc[i][j] = 0.0f;

    for (int c = 0; c < 8; ++c) {  // 8 chunks of 32 dims
      __syncthreads();
      // Stage B chunk: 64 codes x 32 dims, transposed into Bs[dloc][code].
      {
        const int kc = tid >> 2;            // code 0..63
        const int doff = (tid & 3) * 4;     // 0,4,8,12
        const float* cbr = cb + (size_t)(k0 + kc) * DDIM + c * 32;
        float4 v0 = *(const float4*)(cbr + doff);
        float4 v1 = *(const float4*)(cbr + doff + 16);
        Bs[(doff + 0) * 68 + kc] = v0.x;
        Bs[(doff + 1) * 68 + kc] = v0.y;
        Bs[(doff + 2) * 68 + kc] = v0.z;
        Bs[(doff + 3) * 68 + kc] = v0.w;
        Bs[(doff + 16) * 68 + kc] = v1.x;
        Bs[(doff + 17) * 68 + kc] = v1.y;
        Bs[(doff + 18) * 68 + kc] = v1.z;
        Bs[(doff + 19) * 68 + kc] = v1.w;
      }
      __syncthreads();

      const float* Abase = &A[(c * 32) * 64 + ty * 4];
#pragma unroll 4
      for (int dk = 0; dk < 32; ++dk) {
        float a[4], bb[4];
        *(float4*)a = *(const float4*)(Abase + dk * 64);
        *(float4*)bb = *(const float4*)(&Bs[dk * 68 + tx * 4]);
#pragma unroll
        for (int i = 0; i < 4; ++i)
#pragma unroll
          for (int j = 0; j < 4; ++j)
            acc[i][j] = fmaf(a[i], bb[j], acc[i][j]);
      }
    }

    // Apply per-code 1/norm and update running argmax (k strictly increases,
    // so strict > keeps the earliest index on ties, matching jnp.argmax).
#pragma unroll
    for (int j = 0; j < 4; ++j) {
      const int kk = k0 + tx * 4 + j;
      const float rn = rnorm[kk];
#pragma unroll
      for (int i = 0; i < 4; ++i) {
        float v = acc[i][j] * rn;
        if (v > bv[i]) { bv[i] = v; bi[i] = kk; }
      }
    }
  }

  // Cross-tx reduction (16 candidates per token). Reuse Bs as scratch.
  float* redv = Bs;               // 64 tokens x 16 = 1024 floats
  int* redi = (int*)(Bs + 1024);  // 1024 ints
  __syncthreads();
#pragma unroll
  for (int i = 0; i < 4; ++i) {
    redv[(ty * 4 + i) * 16 + tx] = bv[i];
    redi[(ty * 4 + i) * 16 + tx] = bi[i];
  }
  __syncthreads();
  if (tid < 64) {
    float best = -1e30f;
    int bidx = 0x7fffffff;
    for (int t = 0; t < 16; ++t) {
      float v = redv[tid * 16 + t];
      int ix = redi[tid * 16 + t];
      if (v > best || (v == best && ix < bidx)) { best = v; bidx = ix; }
    }
    bestv[(size_t)ks * NTOK + n0 + tid] = best;
    besti[(size_t)ks * NTOK + n0 + tid] = bidx;
  }
}

// ---------------------------------------------------------------------------
// Kernel 3: epilogue. Merge the two K-halves' argmax, gather q0 = cb[idx] *
// rnorm[idx], write q in [B,D,L] layout, accumulate commit-loss partials.
// Thread handles 4 consecutive l at one (b,d).
// ---------------------------------------------------------------------------
__global__ __launch_bounds__(256) void epilogue_kernel(
    const float* __restrict__ x, const float* __restrict__ cb,
    const float* __restrict__ rnorm, const float* __restrict__ bestv,
    const int* __restrict__ besti, float* __restrict__ out,
    float* __restrict__ loss_accum) {
  const size_t gid = (size_t)blockIdx.x * 256 + threadIdx.x;
  const int l4 = (int)(gid & 1023);
  const int bd = (int)(gid >> 10);   // b*256 + d
  const int d = bd & 255;
  const int b = bd >> 8;
  const int l = l4 * 4;
  const int n0 = b * LLEN + l;

  float4 xv = *(const float4*)(x + ((size_t)bd << 12) + l);
  const float* xe = (const float*)&xv;
  float q[4];
  float part = 0.0f;
#pragma unroll
  for (int e = 0; e < 4; ++e) {
    const int n = n0 + e;
    const float v0 = bestv[n];
    const float v1 = bestv[NTOK + n];
    const int idx = (v1 > v0) ? besti[NTOK + n] : besti[n];  // tie -> half 0
    const float qv = cb[(size_t)idx * DDIM + d] * rnorm[idx];
    q[e] = qv;
    const float diff = qv - xe[e];
    part += diff * diff;
  }
  *(float4*)(out + ((size_t)bd << 12) + l) = make_float4(q[0], q[1], q[2], q[3]);

#pragma unroll
  for (int off = 32; off > 0; off >>= 1) part += __shfl_down(part, off);
  if ((threadIdx.x & 63) == 0) atomicAdd(loss_accum, part);
}

// ---------------------------------------------------------------------------
// Kernel 4: finalize commit loss into last output element.
// ---------------------------------------------------------------------------
__global__ void finalize_kernel(const float* __restrict__ loss_accum,
                                float* __restrict__ out_loss) {
  *out_loss = COMMITMENT * (*loss_accum) / (float)((size_t)NTOK * DDIM);
}

extern "C" void kernel_launch(void* const* d_in, const int* in_sizes, int n_in,
                              void* d_out, int out_size, void* d_ws,
                              size_t ws_size, hipStream_t stream) {
  const float* x = (const float*)d_in[0];   // [4,256,4096]
  const float* cb = (const float*)d_in[1];  // [8192,256]
  float* out = (float*)d_out;               // q [4,256,4096] + loss scalar

  // Workspace layout (floats)
  float* ws = (float*)d_ws;
  float* rnorm = ws;                       // 8192
  float* bestv = ws + 8192;                // 2 * 16384
  int* besti = (int*)(ws + 8192 + 2 * NTOK);  // 2 * 16384
  float* lossac = ws + 8192 + 4 * NTOK;    // 1

  rnorm_kernel<<<KCODE / 4, 256, 0, stream>>>(cb, rnorm, lossac);
  simmax_kernel<<<dim3(NTOK / 64, 2), 256, 0, stream>>>(x, cb, rnorm, bestv,
                                                        besti);
  epilogue_kernel<<<(BATCH * DDIM * LLEN / 4) / 256, 256, 0, stream>>>(
      x, cb, rnorm, bestv, besti, out, lossac);
  finalize_kernel<<<1, 1, 0, stream>>>(lossac, out + (out_size - 1));
}

// Round 3
// 459.401 us; speedup vs baseline: 2.8820x; 2.8820x over previous
//
#include <hip/hip_runtime.h>

// Problem constants (fixed by setup_inputs)
#define BATCH 4
#define DDIM 256
#define LLEN 4096
#define NTOK (BATCH * LLEN)   // 16384
#define KCODE 8192
#define COMMITMENT 0.25f
#define MARGIN 0.02f          // dot-units; ~9 sigma of bf16 sim-error diff
#define CAP 48                // candidate slots per token
#define SUBSET 4096           // codes scanned by S0 to build LB

typedef __attribute__((ext_vector_type(8))) short short8;
typedef __attribute__((ext_vector_type(8))) unsigned short ushort8;
typedef __attribute__((ext_vector_type(4))) float f32x4;

__device__ __forceinline__ unsigned short f2bf(float f) {
  unsigned u = __float_as_uint(f);
  unsigned r = (u + 0x7fffu + ((u >> 16) & 1u)) >> 16;
  return (unsigned short)r;
}

__device__ __forceinline__ void gld16(const void* g, void* l) {
  __builtin_amdgcn_global_load_lds(
      (const __attribute__((address_space(1))) unsigned int*)g,
      (__attribute__((address_space(3))) unsigned int*)l, 16, 0, 0);
}

// ---------------------------------------------------------------------------
// P1: transpose x [B,D,L] -> xT fp32 [N,D] and xt_frag bf16 (MFMA frag order).
// Also zero LB/count/loss accumulators. Block = 64 tokens.
// Frag order (row n, dim d): off = (n>>4)*4096 + (d>>5)*512
//                                  + (((d>>3)&3)*16 + (n&15))*8 + (d&7)
// ---------------------------------------------------------------------------
__global__ __launch_bounds__(256) void prep_x_kernel(
    const float* __restrict__ x, float* __restrict__ xT,
    unsigned short* __restrict__ xtf, unsigned int* __restrict__ LB,
    int* __restrict__ count, float* __restrict__ lossac) {
  __shared__ float As[256 * 65];
  const int tid = threadIdx.x;
  const int n0 = blockIdx.x * 64;
  const int b = n0 >> 12, l0 = n0 & 4095;
  const float* xb = x + ((size_t)b << 20) + l0;
  {
    const int t4 = (tid & 15) * 4, dof = tid >> 4;
#pragma unroll
    for (int p = 0; p < 16; ++p) {
      int d = p * 16 + dof;
      float4 v = *(const float4*)(xb + (size_t)d * LLEN + t4);
      As[d * 65 + t4 + 0] = v.x;
      As[d * 65 + t4 + 1] = v.y;
      As[d * 65 + t4 + 2] = v.z;
      As[d * 65 + t4 + 3] = v.w;
    }
  }
  __syncthreads();
  const int tok = tid >> 2, sub = tid & 3;
  const int n = n0 + tok;
#pragma unroll
  for (int q = 0; q < 16; ++q) {
    int d = q * 16 + sub * 4;
    float4 v = make_float4(As[(d + 0) * 65 + tok], As[(d + 1) * 65 + tok],
                           As[(d + 2) * 65 + tok], As[(d + 3) * 65 + tok]);
    *(float4*)(xT + (size_t)n * 256 + d) = v;
  }
#pragma unroll
  for (int q = 0; q < 8; ++q) {
    int d = (sub + q * 4) * 8;
    ushort8 u;
#pragma unroll
    for (int e = 0; e < 8; ++e) u[e] = f2bf(As[(d + e) * 65 + tok]);
    size_t off = ((size_t)(n >> 4)) * 4096 + q * 512 + (sub * 16 + (n & 15)) * 8;
    *(ushort8*)(xtf + off) = u;
  }
  if (tid < 64) {
    LB[n0 + tid] = 0u;
    count[n0 + tid] = 0;
  }
  if (blockIdx.x == 0 && tid == 0) *lossac = 0.0f;
}

// ---------------------------------------------------------------------------
// P2: codebook -> normalized bf16 frags (rnorm folded in) + rnorm fp32.
// Block = 64 codes, 4 threads per code.
// ---------------------------------------------------------------------------
__global__ __launch_bounds__(256) void prep_cb_kernel(
    const float* __restrict__ cb, unsigned short* __restrict__ cbf,
    float* __restrict__ rnorm) {
  const int tid = threadIdx.x;
  const int k = blockIdx.x * 64 + (tid >> 2), sub = tid & 3;
  const float* row = cb + (size_t)k * 256;
  float s = 0.0f;
#pragma unroll
  for (int q = 0; q < 8; ++q) {
    int d = (sub + q * 4) * 8;
    float4 v0 = *(const float4*)(row + d);
    float4 v1 = *(const float4*)(row + d + 4);
    s += v0.x * v0.x + v0.y * v0.y + v0.z * v0.z + v0.w * v0.w;
    s += v1.x * v1.x + v1.y * v1.y + v1.z * v1.z + v1.w * v1.w;
  }
  s += __shfl_xor(s, 1);
  s += __shfl_xor(s, 2);
  float rn = 1.0f / sqrtf(fmaxf(s, 1e-24f));
  if (sub == 0) rnorm[k] = rn;
#pragma unroll
  for (int q = 0; q < 8; ++q) {
    int d = (sub + q * 4) * 8;
    float4 v0 = *(const float4*)(row + d);
    float4 v1 = *(const float4*)(row + d + 4);
    ushort8 u;
    u[0] = f2bf(v0.x * rn); u[1] = f2bf(v0.y * rn);
    u[2] = f2bf(v0.z * rn); u[3] = f2bf(v0.w * rn);
    u[4] = f2bf(v1.x * rn); u[5] = f2bf(v1.y * rn);
    u[6] = f2bf(v1.z * rn); u[7] = f2bf(v1.w * rn);
    size_t off = ((size_t)(k >> 4)) * 4096 + q * 512 + (sub * 16 + (k & 15)) * 8;
    *(ushort8*)(cbf + off) = u;
  }
}

// ---------------------------------------------------------------------------
// S0 (MODE=0): bf16 MFMA max over SUBSET codes -> LB[token] (atomicMax bits).
// S1 (MODE=1): bf16 MFMA over all codes; admit code if sim > LB - MARGIN.
// Block: 256 thr (4 waves), tile 128 tokens x 1024 codes (8 groups of 128).
// A resident (64 KB frag-ordered), B double-buffered 32-dim chunks (2x8 KB).
// ---------------------------------------------------------------------------
template <int MODE>
__global__ __launch_bounds__(256, 2) void simcore_kernel(
    const unsigned short* __restrict__ xtf,
    const unsigned short* __restrict__ cbf, unsigned int* __restrict__ LB,
    int* __restrict__ count, int* __restrict__ cand) {
  __shared__ __align__(16) short Afrag[128 * 256];    // 64 KB
  __shared__ __align__(16) short Bfrag[2][8 * 512];   // 16 KB
  const int tid = threadIdx.x;
  const int w = tid >> 6, lane = tid & 63;
  const int h = w & 1, g = w >> 1;
  const int n0 = blockIdx.x * 128;
  const int code0 = blockIdx.y * 1024;

  // Stage A: 64 KB contiguous copy, 16 wave-rounds of 1 KB.
  {
    const char* src = (const char*)(xtf + (size_t)n0 * 256);
#pragma unroll
    for (int i = 0; i < 16; ++i) {
      int off = (i * 4 + w) << 10;
      gld16(src + off + lane * 16, (char*)Afrag + off);
    }
  }
  // Stage B chunk 0.
  {
    const char* bs = (const char*)(cbf + ((size_t)(code0 >> 4)) * 4096);
#pragma unroll
    for (int r = 0; r < 2; ++r) {
      int tl = r * 4 + w;
      gld16(bs + (size_t)tl * 8192 + lane * 16, (char*)&Bfrag[0][tl * 512]);
    }
  }
  __syncthreads();

  f32x4 acc[4][4];
#pragma unroll
  for (int i = 0; i < 4; ++i)
#pragma unroll
    for (int j = 0; j < 4; ++j) acc[i][j] = (f32x4){0.f, 0.f, 0.f, 0.f};

  float rm[16];
  float lbm[16];
#pragma unroll
  for (int ir = 0; ir < 16; ++ir) rm[ir] = -1e30f;
  if (MODE == 1) {
#pragma unroll
    for (int ir = 0; ir < 16; ++ir) {
      int token = n0 + h * 64 + (ir >> 2) * 16 + ((lane >> 4) << 2) + (ir & 3);
      lbm[ir] = __uint_as_float(LB[token]) - MARGIN;
    }
  }

  for (int cc = 0; cc < 64; ++cc) {
    if (cc < 63) {
      int cc2 = cc + 1;
      const char* bs = (const char*)(cbf + ((size_t)(code0 >> 4) + (cc2 >> 3) * 8) * 4096 +
                                     (cc2 & 7) * 512);
      char* bd = (char*)&Bfrag[cc2 & 1][0];
#pragma unroll
      for (int r = 0; r < 2; ++r) {
        int tl = r * 4 + w;
        gld16(bs + (size_t)tl * 8192 + lane * 16, bd + tl * 1024);
      }
    }
    {
      const int c = cc & 7;
      short8 a[4], bf[4];
#pragma unroll
      for (int i = 0; i < 4; ++i)
        a[i] = *(const short8*)(Afrag + ((h * 4 + i) * 8 + c) * 512 + lane * 8);
#pragma unroll
      for (int j = 0; j < 4; ++j)
        bf[j] = *(const short8*)(&Bfrag[cc & 1][(g * 4 + j) * 512 + lane * 8]);
#pragma unroll
      for (int i = 0; i < 4; ++i)
#pragma unroll
        for (int j = 0; j < 4; ++j)
          acc[i][j] = __builtin_amdgcn_mfma_f32_16x16x32_bf16(a[i], bf[j],
                                                              acc[i][j], 0, 0, 0);
    }
    if ((cc & 7) == 7) {
      const int it = cc >> 3;
      if (MODE == 0) {
#pragma unroll
        for (int i = 0; i < 4; ++i)
#pragma unroll
          for (int j = 0; j < 4; ++j)
#pragma unroll
            for (int r = 0; r < 4; ++r)
              rm[i * 4 + r] = fmaxf(rm[i * 4 + r], acc[i][j][r]);
      } else {
#pragma unroll
        for (int i = 0; i < 4; ++i)
#pragma unroll
          for (int j = 0; j < 4; ++j) {
            bool p0 = acc[i][j][0] > lbm[i * 4 + 0];
            bool p1 = acc[i][j][1] > lbm[i * 4 + 1];
            bool p2 = acc[i][j][2] > lbm[i * 4 + 2];
            bool p3 = acc[i][j][3] > lbm[i * 4 + 3];
            if (__any(p0 | p1 | p2 | p3)) {
#pragma unroll
              for (int r = 0; r < 4; ++r) {
                float v = acc[i][j][r];
                if (v > lbm[i * 4 + r]) {
                  int token = n0 + h * 64 + i * 16 + ((lane >> 4) << 2) + r;
                  int code = code0 + it * 128 + g * 64 + j * 16 + (lane & 15);
                  int slot = atomicAdd(&count[token], 1);
                  if (slot < CAP) cand[(size_t)token * CAP + slot] = code;
                }
              }
            }
          }
      }
#pragma unroll
      for (int i = 0; i < 4; ++i)
#pragma unroll
        for (int j = 0; j < 4; ++j) acc[i][j] = (f32x4){0.f, 0.f, 0.f, 0.f};
    }
    __syncthreads();
  }

  if (MODE == 0) {
#pragma unroll
    for (int ir = 0; ir < 16; ++ir) {
      float v = rm[ir];
      v = fmaxf(v, __shfl_xor(v, 1));
      v = fmaxf(v, __shfl_xor(v, 2));
      v = fmaxf(v, __shfl_xor(v, 4));
      v = fmaxf(v, __shfl_xor(v, 8));
      rm[ir] = v;
    }
    float* LBs = (float*)&Bfrag[0][0];
    if (g == 0 && (lane & 15) == 0) {
#pragma unroll
      for (int ir = 0; ir < 16; ++ir) {
        int tl = h * 64 + (ir >> 2) * 16 + ((lane >> 4) << 2) + (ir & 3);
        LBs[tl] = rm[ir];
      }
    }
    __syncthreads();
    if (g == 1 && (lane & 15) == 0) {
#pragma unroll
      for (int ir = 0; ir < 16; ++ir) {
        int tl = h * 64 + (ir >> 2) * 16 + ((lane >> 4) << 2) + (ir & 3);
        float v = fmaxf(rm[ir], LBs[tl]);
        atomicMax(&LB[n0 + tl], __float_as_uint(v));
      }
    }
  }
}

// ---------------------------------------------------------------------------
// S3: exact fp64 rescore of candidates; one wave per token. Computes
// p/sqrt(sum c^2) in double -> true argmax (error ~1e-13 << min top-2 gap).
// ---------------------------------------------------------------------------
__global__ __launch_bounds__(256) void rescore_kernel(
    const float* __restrict__ xT, const float* __restrict__ cb,
    const int* __restrict__ count, const int* __restrict__ cand,
    int* __restrict__ besti_g) {
  const int w = threadIdx.x >> 6, lane = threadIdx.x & 63;
  const int t = blockIdx.x * 4 + w;
  float4 xv = *(const float4*)(xT + (size_t)t * 256 + lane * 4);
  const double x0 = xv.x, x1 = xv.y, x2 = xv.z, x3 = xv.w;
  int cnt = min(count[t], CAP);
  double bv = -1e300;
  int bi = 1 << 30;
  for (int s = 0; s < cnt; ++s) {
    int k = cand[(size_t)t * CAP + s];
    float4 cv = *(const float4*)(cb + (size_t)k * 256 + lane * 4);
    const double c0 = cv.x, c1 = cv.y, c2 = cv.z, c3 = cv.w;
    double p = x0 * c0 + x1 * c1 + x2 * c2 + x3 * c3;
    double cc = c0 * c0 + c1 * c1 + c2 * c2 + c3 * c3;
#pragma unroll
    for (int m = 1; m < 64; m <<= 1) {
      p += __shfl_xor(p, m);
      cc += __shfl_xor(cc, m);
    }
    double v = p / sqrt(cc);
    if (v > bv || (v == bv && k < bi)) { bv = v; bi = k; }
  }
  if (lane == 0) besti_g[t] = bi;
}

// ---------------------------------------------------------------------------
// Epilogue: gather q0 = cb[idx]*rnorm[idx], write q [B,D,L], commit-loss part.
// ---------------------------------------------------------------------------
__global__ __launch_bounds__(256) void epilogue_kernel(
    const float* __restrict__ x, const float* __restrict__ cb,
    const float* __restrict__ rnorm, const int* __restrict__ besti_g,
    float* __restrict__ out, float* __restrict__ loss_accum) {
  const size_t gid = (size_t)blockIdx.x * 256 + threadIdx.x;
  const int l4 = (int)(gid & 1023);
  const int bd = (int)(gid >> 10);
  const int d = bd & 255;
  const int b = bd >> 8;
  const int l = l4 * 4;
  const int n0 = b * LLEN + l;

  float4 xv = *(const float4*)(x + ((size_t)bd << 12) + l);
  const float* xe = (const float*)&xv;
  int4 idx4 = *(const int4*)(besti_g + n0);
  const int* idxs = (const int*)&idx4;
  float q[4];
  float part = 0.0f;
#pragma unroll
  for (int e = 0; e < 4; ++e) {
    const int idx = idxs[e];
    const float qv = cb[(size_t)idx * DDIM + d] * rnorm[idx];
    q[e] = qv;
    const float diff = qv - xe[e];
    part += diff * diff;
  }
  *(float4*)(out + ((size_t)bd << 12) + l) = make_float4(q[0], q[1], q[2], q[3]);

#pragma unroll
  for (int off = 32; off > 0; off >>= 1) part += __shfl_down(part, off);
  if ((threadIdx.x & 63) == 0) atomicAdd(loss_accum, part);
}

__global__ void finalize_kernel(const float* __restrict__ loss_accum,
                                float* __restrict__ out_loss) {
  *out_loss = COMMITMENT * (*loss_accum) / (float)((size_t)NTOK * DDIM);
}

extern "C" void kernel_launch(void* const* d_in, const int* in_sizes, int n_in,
                              void* d_out, int out_size, void* d_ws,
                              size_t ws_size, hipStream_t stream) {
  const float* x = (const float*)d_in[0];   // [4,256,4096]
  const float* cb = (const float*)d_in[1];  // [8192,256]
  float* out = (float*)d_out;

  char* ws = (char*)d_ws;
  unsigned short* xtf = (unsigned short*)(ws);              // 8 MB
  unsigned short* cbf = (unsigned short*)(ws + 8388608);    // 4 MB
  float* xT = (float*)(ws + 12582912);                      // 16 MB
  int* cand = (int*)(ws + 29360128);                        // 3 MB (16384*48*4)
  float* rnorm = (float*)(ws + 32505856);                   // 32 KB
  unsigned int* LB = (unsigned int*)(ws + 32538624);        // 64 KB
  int* count = (int*)(ws + 32604160);                       // 64 KB
  int* besti = (int*)(ws + 32669696);                       // 64 KB
  float* lossac = (float*)(ws + 32735232);                  // 4 B

  prep_x_kernel<<<NTOK / 64, 256, 0, stream>>>(x, xT, xtf, LB, count, lossac);
  prep_cb_kernel<<<KCODE / 64, 256, 0, stream>>>(cb, cbf, rnorm);
  simcore_kernel<0><<<dim3(NTOK / 128, SUBSET / 1024), 256, 0, stream>>>(
      xtf, cbf, LB, count, cand);
  simcore_kernel<1><<<dim3(NTOK / 128, KCODE / 1024), 256, 0, stream>>>(
      xtf, cbf, LB, count, cand);
  rescore_kernel<<<NTOK / 4, 256, 0, stream>>>(xT, cb, count, cand, besti);
  epilogue_kernel<<<(BATCH * DDIM * LLEN / 4) / 256, 256, 0, stream>>>(
      x, cb, rnorm, besti, out, lossac);
  finalize_kernel<<<1, 1, 0, stream>>>(lossac, out + (out_size - 1));
}

// Round 4
// 255.418 us; speedup vs baseline: 5.1836x; 1.7986x over previous
//
#include <hip/hip_runtime.h>

// Problem constants (fixed by setup_inputs)
#define BATCH 4
#define DDIM 256
#define LLEN 4096
#define NTOK (BATCH * LLEN)   // 16384
#define KCODE 8192
#define COMMITMENT 0.25f
#define MARGIN 0.02f          // dot-units; ~9 sigma of bf16 sim-error diff
#define CAP 48                // candidate slots per token
#define SUBSET 4096           // codes scanned by S0 to build LB

typedef __attribute__((ext_vector_type(8))) short short8;
typedef __attribute__((ext_vector_type(8))) unsigned short ushort8;
typedef __attribute__((ext_vector_type(4))) float f32x4;

__device__ __forceinline__ unsigned short f2bf(float f) {
  unsigned u = __float_as_uint(f);
  unsigned r = (u + 0x7fffu + ((u >> 16) & 1u)) >> 16;
  return (unsigned short)r;
}

__device__ __forceinline__ void gld16(const void* g, void* l) {
  __builtin_amdgcn_global_load_lds(
      (const __attribute__((address_space(1))) unsigned int*)g,
      (__attribute__((address_space(3))) unsigned int*)l, 16, 0, 0);
}

// ---------------------------------------------------------------------------
// P1: transpose x [B,D,L] -> xT fp32 [N,D] and xt_frag bf16 (MFMA frag order).
// Also zero LB/count/loss accumulators. Block = 64 tokens.
// Frag order (row n, dim d): off = (n>>4)*4096 + (d>>5)*512
//                                  + (((d>>3)&3)*16 + (n&15))*8 + (d&7)
// ---------------------------------------------------------------------------
__global__ __launch_bounds__(256) void prep_x_kernel(
    const float* __restrict__ x, float* __restrict__ xT,
    unsigned short* __restrict__ xtf, unsigned int* __restrict__ LB,
    int* __restrict__ count, float* __restrict__ lossac) {
  __shared__ float As[256 * 65];
  const int tid = threadIdx.x;
  const int n0 = blockIdx.x * 64;
  const int b = n0 >> 12, l0 = n0 & 4095;
  const float* xb = x + ((size_t)b << 20) + l0;
  {
    const int t4 = (tid & 15) * 4, dof = tid >> 4;
#pragma unroll
    for (int p = 0; p < 16; ++p) {
      int d = p * 16 + dof;
      float4 v = *(const float4*)(xb + (size_t)d * LLEN + t4);
      As[d * 65 + t4 + 0] = v.x;
      As[d * 65 + t4 + 1] = v.y;
      As[d * 65 + t4 + 2] = v.z;
      As[d * 65 + t4 + 3] = v.w;
    }
  }
  __syncthreads();
  const int tok = tid >> 2, sub = tid & 3;
  const int n = n0 + tok;
#pragma unroll
  for (int q = 0; q < 16; ++q) {
    int d = q * 16 + sub * 4;
    float4 v = make_float4(As[(d + 0) * 65 + tok], As[(d + 1) * 65 + tok],
                           As[(d + 2) * 65 + tok], As[(d + 3) * 65 + tok]);
    *(float4*)(xT + (size_t)n * 256 + d) = v;
  }
#pragma unroll
  for (int q = 0; q < 8; ++q) {
    int d = (sub + q * 4) * 8;
    ushort8 u;
#pragma unroll
    for (int e = 0; e < 8; ++e) u[e] = f2bf(As[(d + e) * 65 + tok]);
    size_t off = ((size_t)(n >> 4)) * 4096 + q * 512 + (sub * 16 + (n & 15)) * 8;
    *(ushort8*)(xtf + off) = u;
  }
  if (tid < 64) {
    LB[n0 + tid] = 0u;
    count[n0 + tid] = 0;
  }
  if (blockIdx.x == 0 && tid == 0) *lossac = 0.0f;
}

// ---------------------------------------------------------------------------
// P2: codebook -> normalized bf16 frags (rnorm folded in) + rnorm fp32.
// Block = 64 codes, 4 threads per code.
// ---------------------------------------------------------------------------
__global__ __launch_bounds__(256) void prep_cb_kernel(
    const float* __restrict__ cb, unsigned short* __restrict__ cbf,
    float* __restrict__ rnorm) {
  const int tid = threadIdx.x;
  const int k = blockIdx.x * 64 + (tid >> 2), sub = tid & 3;
  const float* row = cb + (size_t)k * 256;
  float s = 0.0f;
#pragma unroll
  for (int q = 0; q < 8; ++q) {
    int d = (sub + q * 4) * 8;
    float4 v0 = *(const float4*)(row + d);
    float4 v1 = *(const float4*)(row + d + 4);
    s += v0.x * v0.x + v0.y * v0.y + v0.z * v0.z + v0.w * v0.w;
    s += v1.x * v1.x + v1.y * v1.y + v1.z * v1.z + v1.w * v1.w;
  }
  s += __shfl_xor(s, 1);
  s += __shfl_xor(s, 2);
  float rn = 1.0f / sqrtf(fmaxf(s, 1e-24f));
  if (sub == 0) rnorm[k] = rn;
#pragma unroll
  for (int q = 0; q < 8; ++q) {
    int d = (sub + q * 4) * 8;
    float4 v0 = *(const float4*)(row + d);
    float4 v1 = *(const float4*)(row + d + 4);
    ushort8 u;
    u[0] = f2bf(v0.x * rn); u[1] = f2bf(v0.y * rn);
    u[2] = f2bf(v0.z * rn); u[3] = f2bf(v0.w * rn);
    u[4] = f2bf(v1.x * rn); u[5] = f2bf(v1.y * rn);
    u[6] = f2bf(v1.z * rn); u[7] = f2bf(v1.w * rn);
    size_t off = ((size_t)(k >> 4)) * 4096 + q * 512 + (sub * 16 + (k & 15)) * 8;
    *(ushort8*)(cbf + off) = u;
  }
}

// ---------------------------------------------------------------------------
// S0 (MODE=0): bf16 MFMA max over SUBSET codes -> LB[token] (atomicMax bits).
// S1 (MODE=1): bf16 MFMA over all codes; admit code if sim > LB - MARGIN.
// Block: 256 thr (4 waves), tile 128 tokens x 1024 codes (8 groups of 128).
// A resident (64 KB frag-ordered), B double-buffered 32-dim chunks (2x8 KB).
// ---------------------------------------------------------------------------
template <int MODE>
__global__ __launch_bounds__(256, 2) void simcore_kernel(
    const unsigned short* __restrict__ xtf,
    const unsigned short* __restrict__ cbf, unsigned int* __restrict__ LB,
    int* __restrict__ count, int* __restrict__ cand) {
  __shared__ __align__(16) short Afrag[128 * 256];    // 64 KB
  __shared__ __align__(16) short Bfrag[2][8 * 512];   // 16 KB
  const int tid = threadIdx.x;
  const int w = tid >> 6, lane = tid & 63;
  const int h = w & 1, g = w >> 1;
  const int n0 = blockIdx.x * 128;
  const int code0 = blockIdx.y * 1024;

  // Stage A: 64 KB contiguous copy, 16 wave-rounds of 1 KB.
  {
    const char* src = (const char*)(xtf + (size_t)n0 * 256);
#pragma unroll
    for (int i = 0; i < 16; ++i) {
      int off = (i * 4 + w) << 10;
      gld16(src + off + lane * 16, (char*)Afrag + off);
    }
  }
  // Stage B chunk 0.
  {
    const char* bs = (const char*)(cbf + ((size_t)(code0 >> 4)) * 4096);
#pragma unroll
    for (int r = 0; r < 2; ++r) {
      int tl = r * 4 + w;
      gld16(bs + (size_t)tl * 8192 + lane * 16, (char*)&Bfrag[0][tl * 512]);
    }
  }
  __syncthreads();

  f32x4 acc[4][4];
#pragma unroll
  for (int i = 0; i < 4; ++i)
#pragma unroll
    for (int j = 0; j < 4; ++j) acc[i][j] = (f32x4){0.f, 0.f, 0.f, 0.f};

  float rm[16];
  float lbm[16];
#pragma unroll
  for (int ir = 0; ir < 16; ++ir) rm[ir] = -1e30f;
  if (MODE == 1) {
#pragma unroll
    for (int ir = 0; ir < 16; ++ir) {
      int token = n0 + h * 64 + (ir >> 2) * 16 + ((lane >> 4) << 2) + (ir & 3);
      lbm[ir] = __uint_as_float(LB[token]) - MARGIN;
    }
  }

  for (int cc = 0; cc < 64; ++cc) {
    if (cc < 63) {
      int cc2 = cc + 1;
      const char* bs = (const char*)(cbf + ((size_t)(code0 >> 4) + (cc2 >> 3) * 8) * 4096 +
                                     (cc2 & 7) * 512);
      char* bd = (char*)&Bfrag[cc2 & 1][0];
#pragma unroll
      for (int r = 0; r < 2; ++r) {
        int tl = r * 4 + w;
        gld16(bs + (size_t)tl * 8192 + lane * 16, bd + tl * 1024);
      }
    }
    {
      const int c = cc & 7;
      short8 a[4], bf[4];
#pragma unroll
      for (int i = 0; i < 4; ++i)
        a[i] = *(const short8*)(Afrag + ((h * 4 + i) * 8 + c) * 512 + lane * 8);
#pragma unroll
      for (int j = 0; j < 4; ++j)
        bf[j] = *(const short8*)(&Bfrag[cc & 1][(g * 4 + j) * 512 + lane * 8]);
#pragma unroll
      for (int i = 0; i < 4; ++i)
#pragma unroll
        for (int j = 0; j < 4; ++j)
          acc[i][j] = __builtin_amdgcn_mfma_f32_16x16x32_bf16(a[i], bf[j],
                                                              acc[i][j], 0, 0, 0);
    }
    if ((cc & 7) == 7) {
      const int it = cc >> 3;
      if (MODE == 0) {
#pragma unroll
        for (int i = 0; i < 4; ++i)
#pragma unroll
          for (int j = 0; j < 4; ++j)
#pragma unroll
            for (int r = 0; r < 4; ++r)
              rm[i * 4 + r] = fmaxf(rm[i * 4 + r], acc[i][j][r]);
      } else {
#pragma unroll
        for (int i = 0; i < 4; ++i)
#pragma unroll
          for (int j = 0; j < 4; ++j) {
            bool p0 = acc[i][j][0] > lbm[i * 4 + 0];
            bool p1 = acc[i][j][1] > lbm[i * 4 + 1];
            bool p2 = acc[i][j][2] > lbm[i * 4 + 2];
            bool p3 = acc[i][j][3] > lbm[i * 4 + 3];
            if (__any(p0 | p1 | p2 | p3)) {
#pragma unroll
              for (int r = 0; r < 4; ++r) {
                float v = acc[i][j][r];
                if (v > lbm[i * 4 + r]) {
                  int token = n0 + h * 64 + i * 16 + ((lane >> 4) << 2) + r;
                  int code = code0 + it * 128 + g * 64 + j * 16 + (lane & 15);
                  int slot = atomicAdd(&count[token], 1);
                  if (slot < CAP) cand[(size_t)token * CAP + slot] = code;
                }
              }
            }
          }
      }
#pragma unroll
      for (int i = 0; i < 4; ++i)
#pragma unroll
        for (int j = 0; j < 4; ++j) acc[i][j] = (f32x4){0.f, 0.f, 0.f, 0.f};
    }
    __syncthreads();
  }

  if (MODE == 0) {
#pragma unroll
    for (int ir = 0; ir < 16; ++ir) {
      float v = rm[ir];
      v = fmaxf(v, __shfl_xor(v, 1));
      v = fmaxf(v, __shfl_xor(v, 2));
      v = fmaxf(v, __shfl_xor(v, 4));
      v = fmaxf(v, __shfl_xor(v, 8));
      rm[ir] = v;
    }
    float* LBs = (float*)&Bfrag[0][0];
    if (g == 0 && (lane & 15) == 0) {
#pragma unroll
      for (int ir = 0; ir < 16; ++ir) {
        int tl = h * 64 + (ir >> 2) * 16 + ((lane >> 4) << 2) + (ir & 3);
        LBs[tl] = rm[ir];
      }
    }
    __syncthreads();
    if (g == 1 && (lane & 15) == 0) {
#pragma unroll
      for (int ir = 0; ir < 16; ++ir) {
        int tl = h * 64 + (ir >> 2) * 16 + ((lane >> 4) << 2) + (ir & 3);
        float v = fmaxf(rm[ir], LBs[tl]);
        atomicMax(&LB[n0 + tl], __float_as_uint(v));
      }
    }
  }
}

// ---------------------------------------------------------------------------
// S3: exact fp64 rescore of candidates; one wave per token. Computes
// p/sqrt(sum c^2) in double -> true argmax (error ~1e-13 << min top-2 gap).
// ---------------------------------------------------------------------------
__global__ __launch_bounds__(256) void rescore_kernel(
    const float* __restrict__ xT, const float* __restrict__ cb,
    const int* __restrict__ count, const int* __restrict__ cand,
    int* __restrict__ besti_g) {
  const int w = threadIdx.x >> 6, lane = threadIdx.x & 63;
  const int t = blockIdx.x * 4 + w;
  float4 xv = *(const float4*)(xT + (size_t)t * 256 + lane * 4);
  const double x0 = xv.x, x1 = xv.y, x2 = xv.z, x3 = xv.w;
  int cnt = min(count[t], CAP);
  double bv = -1e300;
  int bi = 1 << 30;
  for (int s = 0; s < cnt; ++s) {
    int k = cand[(size_t)t * CAP + s];
    float4 cv = *(const float4*)(cb + (size_t)k * 256 + lane * 4);
    const double c0 = cv.x, c1 = cv.y, c2 = cv.z, c3 = cv.w;
    double p = x0 * c0 + x1 * c1 + x2 * c2 + x3 * c3;
    double cc = c0 * c0 + c1 * c1 + c2 * c2 + c3 * c3;
#pragma unroll
    for (int m = 1; m < 64; m <<= 1) {
      p += __shfl_xor(p, m);
      cc += __shfl_xor(cc, m);
    }
    double v = p / sqrt(cc);
    if (v > bv || (v == bv && k < bi)) { bv = v; bi = k; }
  }
  if (lane == 0) besti_g[t] = bi;
}

// ---------------------------------------------------------------------------
// Epilogue v2: LDS-staged transpose-gather. Block = 64 tokens (fixed b, l0).
// Phase 1: quad-per-token coalesced gather of cb[idx] (x rnorm) -> QT[d][t].
// Phase 2: coalesced float4 writes of out[b,d,l0..l0+63] + commit-loss.
// One atomicAdd per block.
// ---------------------------------------------------------------------------
__global__ __launch_bounds__(256) void epilogue_kernel(
    const float* __restrict__ x, const float* __restrict__ cb,
    const float* __restrict__ rnorm, const int* __restrict__ besti_g,
    float* __restrict__ out, float* __restrict__ loss_accum) {
  __shared__ float QT[256 * 68];  // QT[d][t], pad 68 (2-way bank alias: free)
  __shared__ int idxs[64];
  __shared__ float lred[4];
  const int tid = threadIdx.x;
  const int n0 = blockIdx.x * 64;
  const int b = n0 >> 12, l0 = n0 & 4095;

  if (tid < 64) idxs[tid] = besti_g[n0 + tid];
  __syncthreads();

  // Phase 1: gather. Each quad loads one code row; per pass a quad reads
  // 64 B contiguous (full cache line), 16 lines per wave instruction.
  {
    const int t = tid >> 2, sub = tid & 3;
    const int idx = idxs[t];
    const float rn = rnorm[idx];
    const float* row = cb + (size_t)idx * 256;
#pragma unroll
    for (int p = 0; p < 16; ++p) {
      const int d = p * 16 + sub * 4;
      float4 v = *(const float4*)(row + d);
      QT[(d + 0) * 68 + t] = v.x * rn;
      QT[(d + 1) * 68 + t] = v.y * rn;
      QT[(d + 2) * 68 + t] = v.z * rn;
      QT[(d + 3) * 68 + t] = v.w * rn;
    }
  }
  __syncthreads();

  // Phase 2: coalesced out writes + loss. Lanes 0..15 share d, cover t.
  float part = 0.0f;
  {
    const int t4 = (tid & 15) * 4;
    const int d0 = tid >> 4;  // 0..15
#pragma unroll
    for (int p = 0; p < 16; ++p) {
      const int d = p * 16 + d0;
      const size_t o = ((size_t)(b * 256 + d) << 12) + l0 + t4;
      float4 q = *(const float4*)(&QT[d * 68 + t4]);
      float4 xv = *(const float4*)(x + o);
      *(float4*)(out + o) = q;
      float e0 = q.x - xv.x, e1 = q.y - xv.y, e2 = q.z - xv.z, e3 = q.w - xv.w;
      part += e0 * e0 + e1 * e1 + e2 * e2 + e3 * e3;
    }
  }
#pragma unroll
  for (int off = 32; off > 0; off >>= 1) part += __shfl_down(part, off);
  const int w = tid >> 6, lane = tid & 63;
  if (lane == 0) lred[w] = part;
  __syncthreads();
  if (tid == 0)
    atomicAdd(loss_accum, lred[0] + lred[1] + lred[2] + lred[3]);
}

__global__ void finalize_kernel(const float* __restrict__ loss_accum,
                                float* __restrict__ out_loss) {
  *out_loss = COMMITMENT * (*loss_accum) / (float)((size_t)NTOK * DDIM);
}

extern "C" void kernel_launch(void* const* d_in, const int* in_sizes, int n_in,
                              void* d_out, int out_size, void* d_ws,
                              size_t ws_size, hipStream_t stream) {
  const float* x = (const float*)d_in[0];   // [4,256,4096]
  const float* cb = (const float*)d_in[1];  // [8192,256]
  float* out = (float*)d_out;

  char* ws = (char*)d_ws;
  unsigned short* xtf = (unsigned short*)(ws);              // 8 MB
  unsigned short* cbf = (unsigned short*)(ws + 8388608);    // 4 MB
  float* xT = (float*)(ws + 12582912);                      // 16 MB
  int* cand = (int*)(ws + 29360128);                        // 3 MB (16384*48*4)
  float* rnorm = (float*)(ws + 32505856);                   // 32 KB
  unsigned int* LB = (unsigned int*)(ws + 32538624);        // 64 KB
  int* count = (int*)(ws + 32604160);                       // 64 KB
  int* besti = (int*)(ws + 32669696);                       // 64 KB
  float* lossac = (float*)(ws + 32735232);                  // 4 B

  prep_x_kernel<<<NTOK / 64, 256, 0, stream>>>(x, xT, xtf, LB, count, lossac);
  prep_cb_kernel<<<KCODE / 64, 256, 0, stream>>>(cb, cbf, rnorm);
  simcore_kernel<0><<<dim3(NTOK / 128, SUBSET / 1024), 256, 0, stream>>>(
      xtf, cbf, LB, count, cand);
  simcore_kernel<1><<<dim3(NTOK / 128, KCODE / 1024), 256, 0, stream>>>(
      xtf, cbf, LB, count, cand);
  rescore_kernel<<<NTOK / 4, 256, 0, stream>>>(xT, cb, count, cand, besti);
  epilogue_kernel<<<NTOK / 64, 256, 0, stream>>>(x, cb, rnorm, besti, out,
                                                 lossac);
  finalize_kernel<<<1, 1, 0, stream>>>(lossac, out + (out_size - 1));
}